// Round 9
// baseline (19746.017 us; speedup 1.0000x reference)
//
#include <hip/hip_runtime.h>

typedef short s16x8 __attribute__((ext_vector_type(8)));
typedef short s16x4 __attribute__((ext_vector_type(4)));
typedef float f32x4 __attribute__((ext_vector_type(4)));
typedef unsigned long long u64;

#define T_N 2048
#define B_N 64
#define H_N 256
#define I_N 256
#define HY_BYTES ((size_t)134217728)   // 4 * T * B * H
#define EXCH_BYTES 65536               // 8 wg x 2 parity x 4KB A-layout blocks
#define WS_NEEDED (EXCH_BYTES + 256)   // + u32 flags[64] (8 wg x 8 waves)

static __device__ __forceinline__ short f2bf(float f) {
    unsigned u = __builtin_bit_cast(unsigned, f);
    u += 0x7FFFu + ((u >> 16) & 1u);   // RNE
    return (short)(u >> 16);
}
static __device__ __forceinline__ float bf2f(short h) {
    unsigned u = ((unsigned)(unsigned short)h) << 16;
    return __builtin_bit_cast(float, u);
}
static __device__ __forceinline__ float e2c(float a) {
    return __builtin_amdgcn_exp2f(fminf(a, 126.0f));
}
static __device__ __forceinline__ s16x4 ntl4(const void* p) {
    return __builtin_nontemporal_load((const s16x4*)p);
}
static __device__ __forceinline__ unsigned umin_(unsigned a, unsigned b) {
    return a < b ? a : b;
}
// min over 8 partner-wave flags (4 x u64 agent loads)
static __device__ __forceinline__ unsigned flags_min8(const u64* fpb) {
    u64 a0 = __hip_atomic_load(&fpb[0], __ATOMIC_RELAXED, __HIP_MEMORY_SCOPE_AGENT);
    u64 a1 = __hip_atomic_load(&fpb[1], __ATOMIC_RELAXED, __HIP_MEMORY_SCOPE_AGENT);
    u64 a2 = __hip_atomic_load(&fpb[2], __ATOMIC_RELAXED, __HIP_MEMORY_SCOPE_AGENT);
    u64 a3 = __hip_atomic_load(&fpb[3], __ATOMIC_RELAXED, __HIP_MEMORY_SCOPE_AGENT);
    unsigned m = umin_((unsigned)a0, (unsigned)(a0 >> 32));
    m = umin_(m, umin_((unsigned)a1, (unsigned)(a1 >> 32)));
    m = umin_(m, umin_((unsigned)a2, (unsigned)(a2 >> 32)));
    m = umin_(m, umin_((unsigned)a3, (unsigned)(a3 >> 32)));
    return m;
}

#define C1 1.44269504088896340f   // log2(e)
#define C2 2.88539008177792681f   // 2*log2(e)

#define MFMA(a, b, c) __builtin_amdgcn_mfma_f32_16x16x32_bf16(a, b, c, 0, 0, 0)

// ---------------------------------------------------------------------------
// Phase 0: zero flags (ws is not re-poisoned per replay).
// ---------------------------------------------------------------------------
__global__ void zero_flags(char* __restrict__ ws) {
    if (threadIdx.x < 64) ((unsigned*)(ws + EXCH_BYTES))[threadIdx.x] = 0u;
}

// ---------------------------------------------------------------------------
// Phase 1: xg = x @ w_ih^T + bias, pre-scaled by -C1 (i,f,o) / -C2 (g),
// bf16 in MFMA C-fragment layout inside d_out (unchanged).
// ---------------------------------------------------------------------------
__global__ __launch_bounds__(512) void xg_gemm(
        const float* __restrict__ x, const float* __restrict__ w_ih,
        const float* __restrict__ b_ih, const float* __restrict__ b_hh,
        char* __restrict__ out)
{
    const int tid  = threadIdx.x;
    const int wave = tid >> 6;
    const int lane = tid & 63;
    const int l15  = lane & 15;
    const int kg   = lane >> 4;

    __shared__ short Blds[8192];

    const int m16 = blockIdx.x * 8 + wave;
    const int by  = blockIdx.y;
    const int n0  = by * 256;

    const float* xrow = x + (size_t)(m16 * 16 + l15) * I_N;

    f32x4 acc[16] = {};

#pragma unroll 1
    for (int ks = 0; ks < 8; ++ks) {
        __syncthreads();
#pragma unroll
        for (int h = 0; h < 2; ++h) {
            int nl = (tid >> 2) + h * 128;
            int c  = tid & 3;
            const float* wp = w_ih + (size_t)(n0 + nl) * I_N + ks * 32 + c * 8;
            f32x4 w0 = *(const f32x4*)(wp);
            f32x4 w1 = *(const f32x4*)(wp + 4);
            s16x8 bv;
            bv[0]=f2bf(w0[0]); bv[1]=f2bf(w0[1]); bv[2]=f2bf(w0[2]); bv[3]=f2bf(w0[3]);
            bv[4]=f2bf(w1[0]); bv[5]=f2bf(w1[1]); bv[6]=f2bf(w1[2]); bv[7]=f2bf(w1[3]);
            int dt = nl >> 4;
            int lp = (nl & 15) + 16 * c;
            *(s16x8*)(&Blds[(dt * 64 + lp) * 8]) = bv;
        }
        __syncthreads();
        const float* ap = xrow + ks * 32 + kg * 8;
        f32x4 a0 = *(const f32x4*)(ap);
        f32x4 a1 = *(const f32x4*)(ap + 4);
        s16x8 av;
        av[0]=f2bf(a0[0]); av[1]=f2bf(a0[1]); av[2]=f2bf(a0[2]); av[3]=f2bf(a0[3]);
        av[4]=f2bf(a1[0]); av[5]=f2bf(a1[1]); av[6]=f2bf(a1[2]); av[7]=f2bf(a1[3]);
#pragma unroll
        for (int dt = 0; dt < 16; ++dt) {
            s16x8 bv = *(const s16x8*)(&Blds[(dt * 64 + lane) * 8]);
            acc[dt] = MFMA(av, bv, acc[dt]);
        }
    }

    const int t = m16 >> 2;
    const int g = m16 & 3;
#pragma unroll
    for (int dt = 0; dt < 16; ++dt) {
        int tau = by * 16 + dt;
        int n   = tau * 16 + l15;
        float bias = b_ih[n] + b_hh[n];
        float scale = ((tau >> 4) == 2) ? -C2 : -C1;
        size_t base = (tau < 32)
            ? ((size_t)t * 65536 + (size_t)g * 16384 + (size_t)tau * 512)
            : (HY_BYTES + (size_t)t * 65536 + (size_t)g * 16384 + (size_t)(tau - 32) * 512);
        s16x4 o;
        o[0] = f2bf(scale * (acc[dt][0] + bias));
        o[1] = f2bf(scale * (acc[dt][1] + bias));
        o[2] = f2bf(scale * (acc[dt][2] + bias));
        o[3] = f2bf(scale * (acc[dt][3] + bias));
        *(s16x4*)(out + base + lane * 8) = o;
    }
}

// ---------------------------------------------------------------------------
// Phase 2: 8 WGs, single barrier per step.  WG b: batch group g=b&3, H-half
// hf=b>>2.  hlds holds ONLY the own half (16x128, 256B rows, XOR-swizzled).
// Exchange: h published at step end DIRECTLY IN A-FRAGMENT LAYOUT (scattered
// u32 agent stores from registers), per-wave flags posted after a cheap
// vmcnt(0); receiver loads partner A-frags straight into MFMA operands
// (no LDS staging, no second barrier).  Flag has ~1 phase of slack.
// ---------------------------------------------------------------------------
__global__ __launch_bounds__(512)
__attribute__((amdgpu_waves_per_eu(2, 2)))
void lstm_rec8(
        const float* __restrict__ h0, const float* __restrict__ c0,
        const float* __restrict__ w_hh, char* __restrict__ out,
        char* __restrict__ ws)
{
    const int b    = blockIdx.x;       // 0..7
    const int g    = b & 3;
    const int hf   = b >> 2;
    const int tid  = threadIdx.x;
    const int w    = tid >> 6;
    const int lane = tid & 63;
    const int l15  = lane & 15;
    const int kg   = lane >> 4;

    const int tc   = hf * 8 + w;       // my global col-tile (0..15)
    const int col  = tc * 16 + l15;    // my global h-col
    const int lc   = w * 16 + l15;     // my col within own half
    const int oks  = 4 * hf;           // own k-slice base (global ks)
    const int pks  = 4 * (hf ^ 1);     // partner k-slice base

    __shared__ short hlds[2][2048];    // 2 x (16 rows x 128 cols) bf16, swizzled

    char* exch_mb = ws + (size_t)b * 8192;         // my blocks (2 parity x 4KB)
    char* exch_pb = ws + (size_t)(b ^ 4) * 8192;   // partner blocks
    unsigned* flags  = (unsigned*)(ws + EXCH_BYTES);
    unsigned* myflag = &flags[b * 8 + w];
    const u64* fpb   = (const u64*)(ws + EXCH_BYTES + (size_t)(b ^ 4) * 32);

    // ---- W fragments: 4 gate tiles, pre-scaled, register(AGPR)-resident ----
    s16x8 wreg[4][8];
#pragma unroll
    for (int q = 0; q < 4; ++q) {
        const int tau = 16 * q + tc;
        const float scale = (q == 2) ? -C2 : -C1;
        const float* wp = w_hh + (size_t)(tau * 16 + l15) * H_N;
#pragma unroll
        for (int ks = 0; ks < 8; ++ks) {
            const float* p = wp + ks * 32 + kg * 8;
            f32x4 w0 = *(const f32x4*)(p);
            f32x4 w1 = *(const f32x4*)(p + 4);
            s16x8 v;
            v[0]=f2bf(scale*w0[0]); v[1]=f2bf(scale*w0[1]);
            v[2]=f2bf(scale*w0[2]); v[3]=f2bf(scale*w0[3]);
            v[4]=f2bf(scale*w1[0]); v[5]=f2bf(scale*w1[1]);
            v[6]=f2bf(scale*w1[2]); v[7]=f2bf(scale*w1[3]);
            wreg[q][ks] = v;
        }
    }

    // ---- h0 own-half -> hlds[0] AND exch block(b,0); flags := 1 ----
    {
        const int row  = tid >> 5;             // 16 rows x 32 threads
        const int col0 = (tid & 31) * 4;       // 4 cols per thread (local)
        const int sw = (row & 7) << 4;
        const float* hp = h0 + (size_t)(g * 16 + row) * H_N + hf * 128 + col0;
        unsigned short bv[4];
#pragma unroll
        for (int j = 0; j < 4; ++j) {
            bv[j] = (unsigned short)f2bf(hp[j]);
            int byte = row * 256 + ((2 * (col0 + j)) ^ sw);
            *(short*)((char*)hlds[0] + byte) = (short)bv[j];
        }
#pragma unroll
        for (int j = 0; j < 4; j += 2) {
            unsigned v32 = (unsigned)bv[j] | ((unsigned)bv[j + 1] << 16);
            int byte = row * 256 + ((2 * (col0 + j)) ^ sw);
            __hip_atomic_store((unsigned*)(exch_mb + byte), v32,
                               __ATOMIC_RELAXED, __HIP_MEMORY_SCOPE_AGENT);
        }
        asm volatile("s_waitcnt vmcnt(0)" ::: "memory");
        if ((tid & 63) == 0)
            __hip_atomic_store(&flags[b * 8 + (tid >> 6)], 1u,
                               __ATOMIC_RELAXED, __HIP_MEMORY_SCOPE_AGENT);
    }

    // ---- c0 -> registers (my cols) ----
    float cst[4];
#pragma unroll
    for (int r = 0; r < 4; ++r)
        cst[r] = c0[(size_t)(g * 16 + kg * 4 + r) * H_N + col];

    float hnew[4] = {};
    unsigned dead = 0;

    __syncthreads();

    const char* p_xg0 = out + (size_t)g * 16384 + (size_t)tc * 512 + (size_t)lane * 8;           // i
    const char* p_xg1 = p_xg0 + 16 * 512;                                                         // f
    const char* p_xg2 = out + HY_BYTES + (size_t)g * 16384 + (size_t)tc * 512 + (size_t)lane * 8; // g
    const char* p_xg3 = p_xg2 + 16 * 512;                                                         // o
    char* st_h = out + (size_t)(g * 16 + kg * 4) * 1024 + (size_t)col * 4;
    char* st_c = st_h + HY_BYTES;

    const int amask = (l15 & 7) << 4;

    s16x4 xg[4];

#define XG_LOAD(T) do {                                                       \
        const size_t _o = ((size_t)(T) << 16);                                \
        xg[0] = ntl4(p_xg0 + _o);  xg[1] = ntl4(p_xg1 + _o);                  \
        xg[2] = ntl4(p_xg2 + _o);  xg[3] = ntl4(p_xg3 + _o);                  \
    } while (0)

    XG_LOAD(0);
    asm volatile("s_waitcnt vmcnt(0)" ::: "memory");

#define STEP(PAR, T) do {                                                     \
        /* h,c of step T-1 -> global (plain cached stores, never waited) */   \
        if ((T) > 0) {                                                        \
            char* _hp = st_h + ((size_t)((T) - 1) << 16);                     \
            char* _cp = st_c + ((size_t)((T) - 1) << 16);                     \
            _Pragma("unroll")                                                 \
            for (int r = 0; r < 4; ++r) {                                     \
                *(float*)(_hp + r * 1024) = hnew[r];                          \
                *(float*)(_cp + r * 1024) = cst[r];                           \
            }                                                                 \
        }                                                                     \
        /* early flag sample (in flight under own-half MFMAs) */              \
        unsigned fm = flags_min8(fpb);                                        \
        /* acc <- pre-scaled xg fragment */                                   \
        f32x4 acc[4];                                                         \
        _Pragma("unroll")                                                     \
        for (int q = 0; q < 4; ++q) {                                         \
            acc[q][0] = bf2f(xg[q][0]); acc[q][1] = bf2f(xg[q][1]);           \
            acc[q][2] = bf2f(xg[q][2]); acc[q][3] = bf2f(xg[q][3]);           \
        }                                                                     \
        /* own-half k-slices from hlds */                                     \
        _Pragma("unroll")                                                     \
        for (int s = 0; s < 4; ++s) {                                         \
            s16x8 av = *(const s16x8*)((const char*)hlds[PAR] +               \
                            l15 * 256 + ((s * 64 + kg * 16) ^ amask));        \
            acc[0] = MFMA(av, wreg[0][oks + s], acc[0]);                      \
            acc[1] = MFMA(av, wreg[1][oks + s], acc[1]);                      \
            acc[2] = MFMA(av, wreg[2][oks + s], acc[2]);                      \
            acc[3] = MFMA(av, wreg[3][oks + s], acc[3]);                      \
        }                                                                     \
        /* confirm partner publish of h(T-1): flags >= T+1 */                 \
        if (fm < (unsigned)((T) + 1) && !dead) {                              \
            unsigned spins = 0;                                               \
            while (flags_min8(fpb) < (unsigned)((T) + 1)) {                   \
                __builtin_amdgcn_s_sleep(1);                                  \
                if (++spins > 8192u) { dead = 1; break; }                     \
            }                                                                 \
        }                                                                     \
        asm volatile("" ::: "memory");                                        \
        /* partner k-slices: A-frags straight from exch block */              \
        {                                                                     \
            const char* _pb = exch_pb + (size_t)(PAR) * 4096;                 \
            _Pragma("unroll")                                                 \
            for (int s = 0; s < 4; ++s) {                                     \
                int off = l15 * 256 + ((s * 64 + kg * 16) ^ amask);           \
                u64 q0 = __hip_atomic_load((const u64*)(_pb + off),           \
                             __ATOMIC_RELAXED, __HIP_MEMORY_SCOPE_AGENT);     \
                u64 q1 = __hip_atomic_load((const u64*)(_pb + off + 8),       \
                             __ATOMIC_RELAXED, __HIP_MEMORY_SCOPE_AGENT);     \
                struct { u64 a, c; } pr = { q0, q1 };                         \
                s16x8 av = __builtin_bit_cast(s16x8, pr);                     \
                acc[0] = MFMA(av, wreg[0][pks + s], acc[0]);                  \
                acc[1] = MFMA(av, wreg[1][pks + s], acc[1]);                  \
                acc[2] = MFMA(av, wreg[2][pks + s], acc[2]);                  \
                acc[3] = MFMA(av, wreg[3][pks + s], acc[3]);                  \
            }                                                                 \
        }                                                                     \
        /* activations */                                                     \
        unsigned pk[4];                                                       \
        _Pragma("unroll")                                                     \
        for (int r = 0; r < 4; ++r) {                                         \
            float Ei = e2c(acc[0][r]);                                        \
            float Ef = e2c(acc[1][r]);                                        \
            float Eg = e2c(acc[2][r]);                                        \
            float Eo = e2c(acc[3][r]);                                        \
            float ai = 1.0f + Ei, af = 1.0f + Ef;                             \
            float ag = 1.0f + Eg, ao = 1.0f + Eo;                             \
            float r1 = __builtin_amdgcn_rcpf(ai * af);                        \
            float gi = r1 * af;                                               \
            float gf = r1 * ai;                                               \
            float r2 = __builtin_amdgcn_rcpf(ag * ao);                        \
            float go = r2 * ag;                                               \
            float tg = 2.0f * (r2 * ao) - 1.0f;                               \
            float c  = gf * cst[r] + gi * tg;                                 \
            cst[r] = c;                                                       \
            float Ec = e2c(-C2 * c);                                          \
            float tc_ = 2.0f * __builtin_amdgcn_rcpf(1.0f + Ec) - 1.0f;       \
            hnew[r] = go * tc_;                                               \
            pk[r] = (unsigned)(unsigned short)f2bf(hnew[r]);                  \
        }                                                                     \
        /* publish h(T) in A-layout -> block(b, PAR^1) (scattered u32) */     \
        if ((T) + 1 < T_N) {                                                  \
            char* _mb = exch_mb + (size_t)((PAR) ^ 1) * 4096;                 \
            _Pragma("unroll")                                                 \
            for (int r = 0; r < 4; ++r) {                                     \
                unsigned nb = __shfl_xor(pk[r], 1, 64);                       \
                if (!(l15 & 1)) {                                             \
                    int row = kg * 4 + r;                                     \
                    int byte = row * 256 + ((2 * lc) ^ ((row & 7) << 4));     \
                    __hip_atomic_store((unsigned*)(_mb + byte),               \
                        pk[r] | (nb << 16),                                   \
                        __ATOMIC_RELAXED, __HIP_MEMORY_SCOPE_AGENT);          \
                }                                                             \
            }                                                                 \
            /* drain publish (xg(T+1) NOT yet issued), post per-wave flag */  \
            asm volatile("s_waitcnt vmcnt(0)" ::: "memory");                  \
            if (lane == 0)                                                    \
                __hip_atomic_store(myflag, (unsigned)((T) + 2),               \
                                   __ATOMIC_RELAXED, __HIP_MEMORY_SCOPE_AGENT);\
            XG_LOAD((T) + 1);                                                 \
        }                                                                     \
        /* own h(T) -> hlds[PAR^1] */                                         \
        _Pragma("unroll")                                                     \
        for (int r = 0; r < 4; ++r) {                                         \
            int row = kg * 4 + r;                                             \
            int byte = row * 256 + ((2 * lc) ^ ((row & 7) << 4));             \
            *(short*)((char*)hlds[(PAR) ^ 1] + byte) = (short)pk[r];          \
        }                                                                     \
        asm volatile("s_waitcnt lgkmcnt(0)" ::: "memory");                    \
        __builtin_amdgcn_s_barrier();                                         \
        asm volatile("" ::: "memory");                                        \
    } while (0)

#pragma unroll 1
    for (int tt = 0; tt < T_N; tt += 2) {
        STEP(0, tt);
        STEP(1, tt + 1);
    }

    // epilogue: h,c of last step + final (hy[-1], cy[-1]) for my cols
    {
        char* hp = st_h + ((size_t)(T_N - 1) << 16);
        char* cp = st_c + ((size_t)(T_N - 1) << 16);
        char* fh = out + 2 * HY_BYTES + (size_t)(g * 16 + kg * 4) * 1024 + (size_t)col * 4;
        char* fc = fh + 65536;
#pragma unroll
        for (int r = 0; r < 4; ++r) {
            *(float*)(hp + r * 1024) = hnew[r];
            *(float*)(cp + r * 1024) = cst[r];
            *(float*)(fh + r * 1024) = hnew[r];
            *(float*)(fc + r * 1024) = cst[r];
        }
    }
#undef STEP
#undef XG_LOAD
}

// ---------------------------------------------------------------------------
// Fallback (ws too small): 4-WG kernel with pre-scaled gates.
// ---------------------------------------------------------------------------
__global__ __launch_bounds__(512)
__attribute__((amdgpu_waves_per_eu(2, 2)))
void lstm_rec_old(
        const float* __restrict__ h0, const float* __restrict__ c0,
        const float* __restrict__ w_hh, char* __restrict__ out)
{
    const int g    = blockIdx.x;
    const int tid  = threadIdx.x;
    const int w    = tid >> 6;
    const int lane = tid & 63;
    const int l15  = lane & 15;
    const int kg   = lane >> 4;

    __shared__ short hlds[2][4096];
    __shared__ short wlds[65536];

    s16x8 wreg[4][8];
    s16x8 wregO[2][8];

#pragma unroll
    for (int d = 0; d < 8; ++d) {
        const int q = d >> 1, ct = d & 1;
        const int tau = 16 * q + 2 * w + ct;
        const float scale = (q == 2) ? -C2 : -C1;
        const float* wp = w_hh + (size_t)(tau * 16 + l15) * H_N;
#pragma unroll
        for (int ks = 0; ks < 8; ++ks) {
            const float* p = wp + ks * 32 + kg * 8;
            f32x4 w0 = *(const f32x4*)(p);
            f32x4 w1 = *(const f32x4*)(p + 4);
            s16x8 v;
            v[0]=f2bf(scale*w0[0]); v[1]=f2bf(scale*w0[1]);
            v[2]=f2bf(scale*w0[2]); v[3]=f2bf(scale*w0[3]);
            v[4]=f2bf(scale*w1[0]); v[5]=f2bf(scale*w1[1]);
            v[6]=f2bf(scale*w1[2]); v[7]=f2bf(scale*w1[3]);
            if (d < 4)      wreg[d][ks] = v;
            else if (d < 6) *(s16x8*)(&wlds[(((w * 2 + (d - 4)) * 8 + ks) * 64 + lane) * 8]) = v;
            else            wregO[d - 6][ks] = v;
        }
    }

    {
        const int row  = tid >> 5;
        const int col0 = (tid & 31) * 8;
        const float* hp = h0 + (size_t)(g * 16 + row) * H_N + col0;
        const int sw = (row & 7) << 4;
#pragma unroll
        for (int j = 0; j < 8; ++j) {
            int byte = row * 512 + ((2 * (col0 + j)) ^ sw);
            *(short*)((char*)hlds[0] + byte) = f2bf(hp[j]);
        }
    }

    float cst[2][4];
#pragma unroll
    for (int ct = 0; ct < 2; ++ct)
#pragma unroll
        for (int r = 0; r < 4; ++r)
            cst[ct][r] = c0[(size_t)(g * 16 + kg * 4 + r) * H_N + 32 * w + 16 * ct + l15];

    float hnew[2][4] = {};
    __syncthreads();

    const char* pxg  = out + (size_t)g * 16384 + (size_t)w * 1024 + (size_t)lane * 8;
    char* st_h = out + (size_t)(g * 16 + kg * 4) * 1024 + (size_t)(32 * w + l15) * 4;
    char* st_c = st_h + HY_BYTES;
    const int amask = (l15 & 7) << 4;

    s16x4 xg[8];
#define XG_LOAD(T) do {                                                       \
        const char* _p = pxg + ((size_t)(T) << 16);                           \
        xg[0] = ntl4(_p);                   xg[1] = ntl4(_p + 512);           \
        xg[2] = ntl4(_p + 8192);            xg[3] = ntl4(_p + 8704);          \
        xg[4] = ntl4(_p + HY_BYTES);        xg[5] = ntl4(_p + HY_BYTES + 512);\
        xg[6] = ntl4(_p + HY_BYTES + 8192); xg[7] = ntl4(_p + HY_BYTES + 8704);\
    } while (0)

    XG_LOAD(0);
    asm volatile("s_waitcnt vmcnt(0)" ::: "memory");

#pragma unroll 1
    for (int t = 0; t < T_N; ++t) {
        const int PAR = t & 1;
        if (t > 0) {
            char* _hp = st_h + ((size_t)(t - 1) << 16);
            char* _cp = st_c + ((size_t)(t - 1) << 16);
#pragma unroll
            for (int ct = 0; ct < 2; ++ct)
#pragma unroll
                for (int r = 0; r < 4; ++r) {
                    *(float*)(_hp + r * 1024 + ct * 64) = hnew[ct][r];
                    *(float*)(_cp + r * 1024 + ct * 64) = cst[ct][r];
                }
        }
        f32x4 acc[8];
#pragma unroll
        for (int d = 0; d < 8; ++d) {
            acc[d][0] = bf2f(xg[d][0]); acc[d][1] = bf2f(xg[d][1]);
            acc[d][2] = bf2f(xg[d][2]); acc[d][3] = bf2f(xg[d][3]);
        }
#pragma unroll
        for (int ks = 0; ks < 8; ++ks) {
            s16x8 av = *(const s16x8*)((const char*)hlds[PAR] +
                            l15 * 512 + ((ks * 64 + kg * 16) ^ amask));
            acc[0] = MFMA(av, wreg[0][ks], acc[0]);
            acc[1] = MFMA(av, wreg[1][ks], acc[1]);
            acc[2] = MFMA(av, wreg[2][ks], acc[2]);
            acc[3] = MFMA(av, wreg[3][ks], acc[3]);
            s16x8 b4 = *(const s16x8*)(&wlds[(((w * 2 + 0) * 8 + ks) * 64 + lane) * 8]);
            acc[4] = MFMA(av, b4, acc[4]);
            s16x8 b5 = *(const s16x8*)(&wlds[(((w * 2 + 1) * 8 + ks) * 64 + lane) * 8]);
            acc[5] = MFMA(av, b5, acc[5]);
            acc[6] = MFMA(av, wregO[0][ks], acc[6]);
            acc[7] = MFMA(av, wregO[1][ks], acc[7]);
        }
        if (t + 1 < T_N) XG_LOAD(t + 1);
#pragma unroll
        for (int ct = 0; ct < 2; ++ct)
#pragma unroll
            for (int r = 0; r < 4; ++r) {
                float Ei = e2c(acc[0 + ct][r]), Ef = e2c(acc[2 + ct][r]);
                float Eg = e2c(acc[4 + ct][r]), Eo = e2c(acc[6 + ct][r]);
                float ai = 1.0f + Ei, af = 1.0f + Ef;
                float ag = 1.0f + Eg, ao = 1.0f + Eo;
                float r1 = __builtin_amdgcn_rcpf(ai * af);
                float gi = r1 * af, gf = r1 * ai;
                float r2 = __builtin_amdgcn_rcpf(ag * ao);
                float go = r2 * ag;
                float tg = 2.0f * (r2 * ao) - 1.0f;
                float c  = gf * cst[ct][r] + gi * tg;
                cst[ct][r] = c;
                float Ec = e2c(-C2 * c);
                float tcv = 2.0f * __builtin_amdgcn_rcpf(1.0f + Ec) - 1.0f;
                hnew[ct][r] = go * tcv;
            }
#pragma unroll
        for (int ct = 0; ct < 2; ++ct)
#pragma unroll
            for (int r = 0; r < 4; ++r) {
                int row = kg * 4 + r;
                int c2 = 32 * w + 16 * ct + l15;
                int byte = row * 512 + ((2 * c2) ^ ((row & 7) << 4));
                *(short*)((char*)hlds[PAR ^ 1] + byte) = f2bf(hnew[ct][r]);
            }
        asm volatile("s_waitcnt lgkmcnt(0)" ::: "memory");
        __builtin_amdgcn_s_barrier();
        asm volatile("" ::: "memory");
    }
    {
        char* hp = st_h + ((size_t)(T_N - 1) << 16);
        char* cp = st_c + ((size_t)(T_N - 1) << 16);
        char* fh = out + 2 * HY_BYTES + (size_t)(g * 16 + kg * 4) * 1024 + (size_t)(32 * w + l15) * 4;
        char* fc = fh + 65536;
#pragma unroll
        for (int ct = 0; ct < 2; ++ct)
#pragma unroll
            for (int r = 0; r < 4; ++r) {
                *(float*)(hp + r * 1024 + ct * 64) = hnew[ct][r];
                *(float*)(cp + r * 1024 + ct * 64) = cst[ct][r];
                *(float*)(fh + r * 1024 + ct * 64) = hnew[ct][r];
                *(float*)(fc + r * 1024 + ct * 64) = cst[ct][r];
            }
    }
#undef XG_LOAD
}

extern "C" void kernel_launch(void* const* d_in, const int* in_sizes, int n_in,
                              void* d_out, int out_size, void* d_ws, size_t ws_size,
                              hipStream_t stream) {
    (void)in_sizes; (void)n_in; (void)out_size;
    const float* x    = (const float*)d_in[0];
    const float* h0   = (const float*)d_in[1];
    const float* c0   = (const float*)d_in[2];
    const float* w_ih = (const float*)d_in[3];
    const float* w_hh = (const float*)d_in[4];
    const float* b_ih = (const float*)d_in[5];
    const float* b_hh = (const float*)d_in[6];
    char* out = (char*)d_out;

    if (ws_size >= WS_NEEDED) {
        zero_flags<<<1, 64, 0, stream>>>((char*)d_ws);
        xg_gemm<<<dim3(1024, 4), 512, 0, stream>>>(x, w_ih, b_ih, b_hh, out);
        lstm_rec8<<<8, 512, 0, stream>>>(h0, c0, w_hh, out, (char*)d_ws);
    } else {
        xg_gemm<<<dim3(1024, 4), 512, 0, stream>>>(x, w_ih, b_ih, b_hh, out);
        lstm_rec_old<<<4, 512, 0, stream>>>(h0, c0, w_hh, out);
    }
}

// Round 10
// 5947.564 us; speedup vs baseline: 3.3200x; 3.3200x over previous
//
#include <hip/hip_runtime.h>

typedef short s16x8 __attribute__((ext_vector_type(8)));
typedef short s16x4 __attribute__((ext_vector_type(4)));
typedef float f32x4 __attribute__((ext_vector_type(4)));
typedef unsigned long long u64;

#define T_N 2048
#define B_N 64
#define H_N 256
#define I_N 256
#define HY_BYTES ((size_t)134217728)   // 4 * T * B * H
#define EXCH_BYTES 65536               // u64[2 parity][8 wg][8 wave][64 lane]
#define WS_NEEDED (EXCH_BYTES + 256)   // + u32 flags[64] (8 wg x 8 waves)

static __device__ __forceinline__ short f2bf(float f) {
    unsigned u = __builtin_bit_cast(unsigned, f);
    u += 0x7FFFu + ((u >> 16) & 1u);   // RNE
    return (short)(u >> 16);
}
static __device__ __forceinline__ float bf2f(short h) {
    unsigned u = ((unsigned)(unsigned short)h) << 16;
    return __builtin_bit_cast(float, u);
}
static __device__ __forceinline__ float e2c(float a) {
    return __builtin_amdgcn_exp2f(fminf(a, 126.0f));
}
static __device__ __forceinline__ s16x4 ntl4(const void* p) {
    return __builtin_nontemporal_load((const s16x4*)p);
}

#define C1 1.44269504088896340f   // log2(e)
#define C2 2.88539008177792681f   // 2*log2(e)

#define MFMA(a, b, c) __builtin_amdgcn_mfma_f32_16x16x32_bf16(a, b, c, 0, 0, 0)

// ---------------------------------------------------------------------------
// Phase 0: zero the pairwise exchange flags (ws not re-poisoned per replay).
// ---------------------------------------------------------------------------
__global__ void zero_flags(char* __restrict__ ws) {
    if (threadIdx.x < 64) ((unsigned*)(ws + EXCH_BYTES))[threadIdx.x] = 0u;
}

// ---------------------------------------------------------------------------
// Phase 1: xg = x @ w_ih^T + bias, pre-scaled by -C1 (i,f,o) / -C2 (g),
// bf16 in MFMA C-fragment layout inside d_out (unchanged).
// ---------------------------------------------------------------------------
__global__ __launch_bounds__(512) void xg_gemm(
        const float* __restrict__ x, const float* __restrict__ w_ih,
        const float* __restrict__ b_ih, const float* __restrict__ b_hh,
        char* __restrict__ out)
{
    const int tid  = threadIdx.x;
    const int wave = tid >> 6;
    const int lane = tid & 63;
    const int l15  = lane & 15;
    const int kg   = lane >> 4;

    __shared__ short Blds[8192];

    const int m16 = blockIdx.x * 8 + wave;
    const int by  = blockIdx.y;
    const int n0  = by * 256;

    const float* xrow = x + (size_t)(m16 * 16 + l15) * I_N;

    f32x4 acc[16] = {};

#pragma unroll 1
    for (int ks = 0; ks < 8; ++ks) {
        __syncthreads();
#pragma unroll
        for (int h = 0; h < 2; ++h) {
            int nl = (tid >> 2) + h * 128;
            int c  = tid & 3;
            const float* wp = w_ih + (size_t)(n0 + nl) * I_N + ks * 32 + c * 8;
            f32x4 w0 = *(const f32x4*)(wp);
            f32x4 w1 = *(const f32x4*)(wp + 4);
            s16x8 bv;
            bv[0]=f2bf(w0[0]); bv[1]=f2bf(w0[1]); bv[2]=f2bf(w0[2]); bv[3]=f2bf(w0[3]);
            bv[4]=f2bf(w1[0]); bv[5]=f2bf(w1[1]); bv[6]=f2bf(w1[2]); bv[7]=f2bf(w1[3]);
            int dt = nl >> 4;
            int lp = (nl & 15) + 16 * c;
            *(s16x8*)(&Blds[(dt * 64 + lp) * 8]) = bv;
        }
        __syncthreads();
        const float* ap = xrow + ks * 32 + kg * 8;
        f32x4 a0 = *(const f32x4*)(ap);
        f32x4 a1 = *(const f32x4*)(ap + 4);
        s16x8 av;
        av[0]=f2bf(a0[0]); av[1]=f2bf(a0[1]); av[2]=f2bf(a0[2]); av[3]=f2bf(a0[3]);
        av[4]=f2bf(a1[0]); av[5]=f2bf(a1[1]); av[6]=f2bf(a1[2]); av[7]=f2bf(a1[3]);
#pragma unroll
        for (int dt = 0; dt < 16; ++dt) {
            s16x8 bv = *(const s16x8*)(&Blds[(dt * 64 + lane) * 8]);
            acc[dt] = MFMA(av, bv, acc[dt]);
        }
    }

    const int t = m16 >> 2;
    const int g = m16 & 3;
#pragma unroll
    for (int dt = 0; dt < 16; ++dt) {
        int tau = by * 16 + dt;
        int n   = tau * 16 + l15;
        float bias = b_ih[n] + b_hh[n];
        float scale = ((tau >> 4) == 2) ? -C2 : -C1;
        size_t base = (tau < 32)
            ? ((size_t)t * 65536 + (size_t)g * 16384 + (size_t)tau * 512)
            : (HY_BYTES + (size_t)t * 65536 + (size_t)g * 16384 + (size_t)(tau - 32) * 512);
        s16x4 o;
        o[0] = f2bf(scale * (acc[dt][0] + bias));
        o[1] = f2bf(scale * (acc[dt][1] + bias));
        o[2] = f2bf(scale * (acc[dt][2] + bias));
        o[3] = f2bf(scale * (acc[dt][3] + bias));
        *(s16x4*)(out + base + lane * 8) = o;
    }
}

// ---------------------------------------------------------------------------
// Phase 2: round-7 structure (best measured: 9.18 ms) with two exchange trims:
//  - pairwise per-wave flags (plain agent store / single u32 poll) replacing
//    the 8-wave serialized fetch_add chain on one cacheline
//  - xg prefetch issued AFTER the flag post, so the pre-flag vmcnt(0) drains
//    only the publish store (hy/cy stores are a full step old)
// Everything else identical to round 7.  Sticky bounded poll: broken sync
// produces a fast absmax failure, never a hung container.
// ---------------------------------------------------------------------------
__global__ __launch_bounds__(512)
__attribute__((amdgpu_waves_per_eu(2, 2)))
void lstm_rec8(
        const float* __restrict__ h0, const float* __restrict__ c0,
        const float* __restrict__ w_hh, char* __restrict__ out,
        char* __restrict__ ws)
{
    const int b    = blockIdx.x;       // 0..7
    const int g    = b & 3;
    const int hf   = b >> 2;
    const int tid  = threadIdx.x;
    const int w    = tid >> 6;
    const int lane = tid & 63;
    const int l15  = lane & 15;
    const int kg   = lane >> 4;

    const int tc   = hf * 8 + w;       // my col-tile (0..15)
    const int ptc  = (hf ^ 1) * 8 + w; // partner col-tile staged by this wave
    const int col  = tc * 16 + l15;
    const int pcol = ptc * 16 + l15;

    __shared__ short hlds[2][4096];    // double-buffered 16x256 bf16, swizzled

    unsigned long long* exch = (unsigned long long*)ws;
    unsigned* flags = (unsigned*)(ws + EXCH_BYTES);
    const size_t myx = ((size_t)b * 8 + w) * 64 + lane;
    const size_t pbx = ((size_t)(b ^ 4) * 8 + w) * 64 + lane;
    unsigned* myflag = &flags[b * 8 + w];          // pairwise: wave w <-> wave w
    unsigned* pflag  = &flags[(b ^ 4) * 8 + w];

    // ---- W fragments: 4 gate tiles, pre-scaled, register-resident ----
    s16x8 wreg[4][8];
#pragma unroll
    for (int q = 0; q < 4; ++q) {
        const int tau = 16 * q + tc;
        const float scale = (q == 2) ? -C2 : -C1;
        const float* wp = w_hh + (size_t)(tau * 16 + l15) * H_N;
#pragma unroll
        for (int ks = 0; ks < 8; ++ks) {
            const float* p = wp + ks * 32 + kg * 8;
            f32x4 w0 = *(const f32x4*)(p);
            f32x4 w1 = *(const f32x4*)(p + 4);
            s16x8 v;
            v[0]=f2bf(scale*w0[0]); v[1]=f2bf(scale*w0[1]);
            v[2]=f2bf(scale*w0[2]); v[3]=f2bf(scale*w0[3]);
            v[4]=f2bf(scale*w1[0]); v[5]=f2bf(scale*w1[1]);
            v[6]=f2bf(scale*w1[2]); v[7]=f2bf(scale*w1[3]);
            wreg[q][ks] = v;
        }
    }

    // ---- h0 -> hlds[0] (full 256 cols, bf16, XOR swizzle per row) ----
    {
        const int row  = tid >> 5;
        const int col0 = (tid & 31) * 8;
        const float* hp = h0 + (size_t)(g * 16 + row) * H_N + col0;
        const int sw = (row & 7) << 4;
#pragma unroll
        for (int j = 0; j < 8; ++j) {
            int byte = row * 512 + ((2 * (col0 + j)) ^ sw);
            *(short*)((char*)hlds[0] + byte) = f2bf(hp[j]);
        }
    }

    // ---- c0 -> registers (my cols only) ----
    float cst[4];
#pragma unroll
    for (int r = 0; r < 4; ++r)
        cst[r] = c0[(size_t)(g * 16 + kg * 4 + r) * H_N + col];

    float hnew[4] = {};
    unsigned dead = 0;    // sticky poll-timeout marker

    __syncthreads();

    const char* p_xg0 = out + (size_t)g * 16384 + (size_t)tc * 512 + (size_t)lane * 8;           // i
    const char* p_xg1 = p_xg0 + 16 * 512;                                                         // f
    const char* p_xg2 = out + HY_BYTES + (size_t)g * 16384 + (size_t)tc * 512 + (size_t)lane * 8; // g
    const char* p_xg3 = p_xg2 + 16 * 512;                                                         // o
    char* st_h = out + (size_t)(g * 16 + kg * 4) * 1024 + (size_t)col * 4;
    char* st_c = st_h + HY_BYTES;

    const int amask = (l15 & 7) << 4;

    s16x4 xg[4];

#define XG_LOAD(T) do {                                                       \
        const size_t _o = ((size_t)(T) << 16);                                \
        xg[0] = ntl4(p_xg0 + _o);  xg[1] = ntl4(p_xg1 + _o);                  \
        xg[2] = ntl4(p_xg2 + _o);  xg[3] = ntl4(p_xg3 + _o);                  \
    } while (0)

    XG_LOAD(0);
    asm volatile("s_waitcnt vmcnt(0)" ::: "memory");

#define STEP(PAR, T) do {                                                     \
        /* h,c outputs of step T-1 (cached stores; never waited on) */        \
        if ((T) > 0) {                                                        \
            char* _hp = st_h + ((size_t)((T) - 1) << 16);                     \
            char* _cp = st_c + ((size_t)((T) - 1) << 16);                     \
            _Pragma("unroll")                                                 \
            for (int r = 0; r < 4; ++r) {                                     \
                *(float*)(_hp + r * 1024) = hnew[r];                          \
                *(float*)(_cp + r * 1024) = cst[r];                           \
            }                                                                 \
        }                                                                     \
        /* early flag sample (in flight during the MFMAs) */                  \
        unsigned fv = __hip_atomic_load(pflag, __ATOMIC_RELAXED,              \
                                        __HIP_MEMORY_SCOPE_AGENT);            \
        /* acc <- pre-scaled xg fragment (identical layout) */                \
        f32x4 acc[4];                                                         \
        _Pragma("unroll")                                                     \
        for (int q = 0; q < 4; ++q) {                                         \
            acc[q][0] = bf2f(xg[q][0]); acc[q][1] = bf2f(xg[q][1]);           \
            acc[q][2] = bf2f(xg[q][2]); acc[q][3] = bf2f(xg[q][3]);           \
        }                                                                     \
        /* gates += h_T @ (scaled W)^T  (full k=256; W in regs) */            \
        _Pragma("unroll")                                                     \
        for (int ks = 0; ks < 8; ++ks) {                                      \
            s16x8 av = *(const s16x8*)((const char*)hlds[PAR] +               \
                            l15 * 512 + ((ks * 64 + kg * 16) ^ amask));       \
            acc[0] = MFMA(av, wreg[0][ks], acc[0]);                           \
            acc[1] = MFMA(av, wreg[1][ks], acc[1]);                           \
            acc[2] = MFMA(av, wreg[2][ks], acc[2]);                           \
            acc[3] = MFMA(av, wreg[3][ks], acc[3]);                           \
        }                                                                     \
        /* activations (exp2 fed directly by pre-scaled gates) */             \
        unsigned pk0, pk1;                                                    \
        {                                                                     \
            _Pragma("unroll")                                                 \
            for (int r = 0; r < 4; ++r) {                                     \
                float Ei = e2c(acc[0][r]);                                    \
                float Ef = e2c(acc[1][r]);                                    \
                float Eg = e2c(acc[2][r]);                                    \
                float Eo = e2c(acc[3][r]);                                    \
                float ai = 1.0f + Ei, af = 1.0f + Ef;                         \
                float ag = 1.0f + Eg, ao = 1.0f + Eo;                         \
                float r1 = __builtin_amdgcn_rcpf(ai * af);                    \
                float gi = r1 * af;                                           \
                float gf = r1 * ai;                                           \
                float r2 = __builtin_amdgcn_rcpf(ag * ao);                    \
                float go = r2 * ag;                                           \
                float tg = 2.0f * (r2 * ao) - 1.0f;                           \
                float c  = gf * cst[r] + gi * tg;                             \
                cst[r] = c;                                                   \
                float Ec = e2c(-C2 * c);                                      \
                float tc_ = 2.0f * __builtin_amdgcn_rcpf(1.0f + Ec) - 1.0f;   \
                hnew[r] = go * tc_;                                           \
            }                                                                 \
            unsigned s0 = (unsigned short)f2bf(hnew[0]);                      \
            unsigned s1 = (unsigned short)f2bf(hnew[1]);                      \
            unsigned s2 = (unsigned short)f2bf(hnew[2]);                      \
            unsigned s3 = (unsigned short)f2bf(hnew[3]);                      \
            pk0 = s0 | (s1 << 16);                                            \
            pk1 = s2 | (s3 << 16);                                            \
            /* own-half h -> hlds[PAR^1] */                                   \
            _Pragma("unroll")                                                 \
            for (int r = 0; r < 4; ++r) {                                     \
                int row = kg * 4 + r;                                         \
                int byte = row * 512 + ((2 * col) ^ ((row & 7) << 4));        \
                unsigned v = (r < 2) ? pk0 : pk1;                             \
                *(short*)((char*)hlds[(PAR) ^ 1] + byte) =                    \
                    (short)((r & 1) ? (v >> 16) : v);                         \
            }                                                                 \
        }                                                                     \
        if ((T) + 1 < T_N) {                                                  \
            /* publish my 4 values; drain covers ONLY this store (hy/cy are */\
            /* a full step old); then pairwise flag; then xg prefetch */      \
            unsigned long long val = ((unsigned long long)pk1 << 32) | pk0;   \
            __hip_atomic_store(exch + (size_t)(PAR) * 4096 + myx, val,        \
                               __ATOMIC_RELAXED, __HIP_MEMORY_SCOPE_AGENT);   \
            asm volatile("s_waitcnt vmcnt(0)" ::: "memory");                  \
            if (lane == 0)                                                    \
                __hip_atomic_store(myflag, (unsigned)((T) + 1),               \
                                   __ATOMIC_RELAXED,                          \
                                   __HIP_MEMORY_SCOPE_AGENT);                 \
            XG_LOAD((T) + 1);                                                 \
            /* partner half: bounded poll, read, stage into hlds[PAR^1] */    \
            if (fv < (unsigned)((T) + 1) && !dead) {                          \
                unsigned spins = 0;                                           \
                while (__hip_atomic_load(pflag, __ATOMIC_RELAXED,             \
                                         __HIP_MEMORY_SCOPE_AGENT)           \
                       < (unsigned)((T) + 1)) {                               \
                    __builtin_amdgcn_s_sleep(1);                              \
                    if (++spins > 16384u) { dead = 1; break; }                \
                }                                                             \
            }                                                                 \
            unsigned long long pv = __hip_atomic_load(                        \
                exch + (size_t)(PAR) * 4096 + pbx,                            \
                __ATOMIC_RELAXED, __HIP_MEMORY_SCOPE_AGENT);                  \
            _Pragma("unroll")                                                 \
            for (int r = 0; r < 4; ++r) {                                     \
                int row = kg * 4 + r;                                         \
                int byte = row * 512 + ((2 * pcol) ^ ((row & 7) << 4));       \
                *(short*)((char*)hlds[(PAR) ^ 1] + byte) =                    \
                    (short)(pv >> (16 * r));                                  \
            }                                                                 \
        }                                                                     \
        /* single barrier per step: all LDS writes visible */                 \
        asm volatile("s_waitcnt lgkmcnt(0)" ::: "memory");                    \
        __builtin_amdgcn_s_barrier();                                         \
        asm volatile("" ::: "memory");                                        \
    } while (0)

#pragma unroll 1
    for (int tt = 0; tt < T_N; tt += 2) {
        STEP(0, tt);
        STEP(1, tt + 1);
    }

    // epilogue: h,c of last step + final (hy[-1], cy[-1]) for my cols
    {
        char* hp = st_h + ((size_t)(T_N - 1) << 16);
        char* cp = st_c + ((size_t)(T_N - 1) << 16);
        char* fh = out + 2 * HY_BYTES + (size_t)(g * 16 + kg * 4) * 1024 + (size_t)col * 4;
        char* fc = fh + 65536;
#pragma unroll
        for (int r = 0; r < 4; ++r) {
            *(float*)(hp + r * 1024) = hnew[r];
            *(float*)(cp + r * 1024) = cst[r];
            *(float*)(fh + r * 1024) = hnew[r];
            *(float*)(fc + r * 1024) = cst[r];
        }
    }
#undef STEP
#undef XG_LOAD
}

// ---------------------------------------------------------------------------
// Fallback (ws too small): 4-WG kernel with pre-scaled gates.
// ---------------------------------------------------------------------------
__global__ __launch_bounds__(512)
__attribute__((amdgpu_waves_per_eu(2, 2)))
void lstm_rec_old(
        const float* __restrict__ h0, const float* __restrict__ c0,
        const float* __restrict__ w_hh, char* __restrict__ out)
{
    const int g    = blockIdx.x;
    const int tid  = threadIdx.x;
    const int w    = tid >> 6;
    const int lane = tid & 63;
    const int l15  = lane & 15;
    const int kg   = lane >> 4;

    __shared__ short hlds[2][4096];
    __shared__ short wlds[65536];

    s16x8 wreg[4][8];
    s16x8 wregO[2][8];

#pragma unroll
    for (int d = 0; d < 8; ++d) {
        const int q = d >> 1, ct = d & 1;
        const int tau = 16 * q + 2 * w + ct;
        const float scale = (q == 2) ? -C2 : -C1;
        const float* wp = w_hh + (size_t)(tau * 16 + l15) * H_N;
#pragma unroll
        for (int ks = 0; ks < 8; ++ks) {
            const float* p = wp + ks * 32 + kg * 8;
            f32x4 w0 = *(const f32x4*)(p);
            f32x4 w1 = *(const f32x4*)(p + 4);
            s16x8 v;
            v[0]=f2bf(scale*w0[0]); v[1]=f2bf(scale*w0[1]);
            v[2]=f2bf(scale*w0[2]); v[3]=f2bf(scale*w0[3]);
            v[4]=f2bf(scale*w1[0]); v[5]=f2bf(scale*w1[1]);
            v[6]=f2bf(scale*w1[2]); v[7]=f2bf(scale*w1[3]);
            if (d < 4)      wreg[d][ks] = v;
            else if (d < 6) *(s16x8*)(&wlds[(((w * 2 + (d - 4)) * 8 + ks) * 64 + lane) * 8]) = v;
            else            wregO[d - 6][ks] = v;
        }
    }

    {
        const int row  = tid >> 5;
        const int col0 = (tid & 31) * 8;
        const float* hp = h0 + (size_t)(g * 16 + row) * H_N + col0;
        const int sw = (row & 7) << 4;
#pragma unroll
        for (int j = 0; j < 8; ++j) {
            int byte = row * 512 + ((2 * (col0 + j)) ^ sw);
            *(short*)((char*)hlds[0] + byte) = f2bf(hp[j]);
        }
    }

    float cst[2][4];
#pragma unroll
    for (int ct = 0; ct < 2; ++ct)
#pragma unroll
        for (int r = 0; r < 4; ++r)
            cst[ct][r] = c0[(size_t)(g * 16 + kg * 4 + r) * H_N + 32 * w + 16 * ct + l15];

    float hnew[2][4] = {};
    __syncthreads();

    const char* pxg  = out + (size_t)g * 16384 + (size_t)w * 1024 + (size_t)lane * 8;
    char* st_h = out + (size_t)(g * 16 + kg * 4) * 1024 + (size_t)(32 * w + l15) * 4;
    char* st_c = st_h + HY_BYTES;
    const int amask = (l15 & 7) << 4;

    s16x4 xg[8];
#define XG_LOAD(T) do {                                                       \
        const char* _p = pxg + ((size_t)(T) << 16);                           \
        xg[0] = ntl4(_p);                   xg[1] = ntl4(_p + 512);           \
        xg[2] = ntl4(_p + 8192);            xg[3] = ntl4(_p + 8704);          \
        xg[4] = ntl4(_p + HY_BYTES);        xg[5] = ntl4(_p + HY_BYTES + 512);\
        xg[6] = ntl4(_p + HY_BYTES + 8192); xg[7] = ntl4(_p + HY_BYTES + 8704);\
    } while (0)

    XG_LOAD(0);
    asm volatile("s_waitcnt vmcnt(0)" ::: "memory");

#pragma unroll 1
    for (int t = 0; t < T_N; ++t) {
        const int PAR = t & 1;
        if (t > 0) {
            char* _hp = st_h + ((size_t)(t - 1) << 16);
            char* _cp = st_c + ((size_t)(t - 1) << 16);
#pragma unroll
            for (int ct = 0; ct < 2; ++ct)
#pragma unroll
                for (int r = 0; r < 4; ++r) {
                    *(float*)(_hp + r * 1024 + ct * 64) = hnew[ct][r];
                    *(float*)(_cp + r * 1024 + ct * 64) = cst[ct][r];
                }
        }
        f32x4 acc[8];
#pragma unroll
        for (int d = 0; d < 8; ++d) {
            acc[d][0] = bf2f(xg[d][0]); acc[d][1] = bf2f(xg[d][1]);
            acc[d][2] = bf2f(xg[d][2]); acc[d][3] = bf2f(xg[d][3]);
        }
#pragma unroll
        for (int ks = 0; ks < 8; ++ks) {
            s16x8 av = *(const s16x8*)((const char*)hlds[PAR] +
                            l15 * 512 + ((ks * 64 + kg * 16) ^ amask));
            acc[0] = MFMA(av, wreg[0][ks], acc[0]);
            acc[1] = MFMA(av, wreg[1][ks], acc[1]);
            acc[2] = MFMA(av, wreg[2][ks], acc[2]);
            acc[3] = MFMA(av, wreg[3][ks], acc[3]);
            s16x8 b4 = *(const s16x8*)(&wlds[(((w * 2 + 0) * 8 + ks) * 64 + lane) * 8]);
            acc[4] = MFMA(av, b4, acc[4]);
            s16x8 b5 = *(const s16x8*)(&wlds[(((w * 2 + 1) * 8 + ks) * 64 + lane) * 8]);
            acc[5] = MFMA(av, b5, acc[5]);
            acc[6] = MFMA(av, wregO[0][ks], acc[6]);
            acc[7] = MFMA(av, wregO[1][ks], acc[7]);
        }
        if (t + 1 < T_N) XG_LOAD(t + 1);
#pragma unroll
        for (int ct = 0; ct < 2; ++ct)
#pragma unroll
            for (int r = 0; r < 4; ++r) {
                float Ei = e2c(acc[0 + ct][r]), Ef = e2c(acc[2 + ct][r]);
                float Eg = e2c(acc[4 + ct][r]), Eo = e2c(acc[6 + ct][r]);
                float ai = 1.0f + Ei, af = 1.0f + Ef;
                float ag = 1.0f + Eg, ao = 1.0f + Eo;
                float r1 = __builtin_amdgcn_rcpf(ai * af);
                float gi = r1 * af, gf = r1 * ai;
                float r2 = __builtin_amdgcn_rcpf(ag * ao);
                float go = r2 * ag;
                float tg = 2.0f * (r2 * ao) - 1.0f;
                float c  = gf * cst[ct][r] + gi * tg;
                cst[ct][r] = c;
                float Ec = e2c(-C2 * c);
                float tcv = 2.0f * __builtin_amdgcn_rcpf(1.0f + Ec) - 1.0f;
                hnew[ct][r] = go * tcv;
            }
#pragma unroll
        for (int ct = 0; ct < 2; ++ct)
#pragma unroll
            for (int r = 0; r < 4; ++r) {
                int row = kg * 4 + r;
                int c2 = 32 * w + 16 * ct + l15;
                int byte = row * 512 + ((2 * c2) ^ ((row & 7) << 4));
                *(short*)((char*)hlds[PAR ^ 1] + byte) = f2bf(hnew[ct][r]);
            }
        asm volatile("s_waitcnt lgkmcnt(0)" ::: "memory");
        __builtin_amdgcn_s_barrier();
        asm volatile("" ::: "memory");
    }
    {
        char* hp = st_h + ((size_t)(T_N - 1) << 16);
        char* cp = st_c + ((size_t)(T_N - 1) << 16);
        char* fh = out + 2 * HY_BYTES + (size_t)(g * 16 + kg * 4) * 1024 + (size_t)(32 * w + l15) * 4;
        char* fc = fh + 65536;
#pragma unroll
        for (int ct = 0; ct < 2; ++ct)
#pragma unroll
            for (int r = 0; r < 4; ++r) {
                *(float*)(hp + r * 1024 + ct * 64) = hnew[ct][r];
                *(float*)(cp + r * 1024 + ct * 64) = cst[ct][r];
                *(float*)(fh + r * 1024 + ct * 64) = hnew[ct][r];
                *(float*)(fc + r * 1024 + ct * 64) = cst[ct][r];
            }
    }
#undef XG_LOAD
}

extern "C" void kernel_launch(void* const* d_in, const int* in_sizes, int n_in,
                              void* d_out, int out_size, void* d_ws, size_t ws_size,
                              hipStream_t stream) {
    (void)in_sizes; (void)n_in; (void)out_size;
    const float* x    = (const float*)d_in[0];
    const float* h0   = (const float*)d_in[1];
    const float* c0   = (const float*)d_in[2];
    const float* w_ih = (const float*)d_in[3];
    const float* w_hh = (const float*)d_in[4];
    const float* b_ih = (const float*)d_in[5];
    const float* b_hh = (const float*)d_in[6];
    char* out = (char*)d_out;

    if (ws_size >= WS_NEEDED) {
        zero_flags<<<1, 64, 0, stream>>>((char*)d_ws);
        xg_gemm<<<dim3(1024, 4), 512, 0, stream>>>(x, w_ih, b_ih, b_hh, out);
        lstm_rec8<<<8, 512, 0, stream>>>(h0, c0, w_hh, out, (char*)d_ws);
    } else {
        xg_gemm<<<dim3(1024, 4), 512, 0, stream>>>(x, w_ih, b_ih, b_hh, out);
        lstm_rec_old<<<4, 512, 0, stream>>>(h0, c0, w_hh, out);
    }
}

// Round 11
// 4758.399 us; speedup vs baseline: 4.1497x; 1.2499x over previous
//
#include <hip/hip_runtime.h>

typedef short s16x8 __attribute__((ext_vector_type(8)));
typedef short s16x4 __attribute__((ext_vector_type(4)));
typedef float f32x4 __attribute__((ext_vector_type(4)));
typedef unsigned long long u64;

#define T_N 2048
#define B_N 64
#define H_N 256
#define I_N 256
#define HY_BYTES ((size_t)134217728)   // 4 * T * B * H
// v2: exch u64[2 parity][8 wg][8 wave][64 lane][2] = 128 KB, data|ctr fused
#define WS_V2 131072
// v1 (r10): exch 64KB + u32 flags[64]
#define EXCH_BYTES 65536
#define WS_V1 (EXCH_BYTES + 256)

static __device__ __forceinline__ short f2bf(float f) {
    unsigned u = __builtin_bit_cast(unsigned, f);
    u += 0x7FFFu + ((u >> 16) & 1u);   // RNE
    return (short)(u >> 16);
}
static __device__ __forceinline__ float bf2f(short h) {
    unsigned u = ((unsigned)(unsigned short)h) << 16;
    return __builtin_bit_cast(float, u);
}
static __device__ __forceinline__ float e2c(float a) {
    return __builtin_amdgcn_exp2f(fminf(a, 126.0f));
}
static __device__ __forceinline__ s16x4 ntl4(const void* p) {
    return __builtin_nontemporal_load((const s16x4*)p);
}

#define C1 1.44269504088896340f   // log2(e)
#define C2 2.88539008177792681f   // 2*log2(e)

#define MFMA(a, b, c) __builtin_amdgcn_mfma_f32_16x16x32_bf16(a, b, c, 0, 0, 0)

// ---------------------------------------------------------------------------
// zero flags (v1 fallback path only; ws not re-poisoned per replay)
// ---------------------------------------------------------------------------
__global__ void zero_flags(char* __restrict__ ws) {
    if (threadIdx.x < 64) ((unsigned*)(ws + EXCH_BYTES))[threadIdx.x] = 0u;
}

// ---------------------------------------------------------------------------
// Phase 1: xg = x @ w_ih^T + bias, pre-scaled by -C1 (i,f,o) / -C2 (g),
// bf16 in MFMA C-fragment layout inside d_out (unchanged).
// ---------------------------------------------------------------------------
__global__ __launch_bounds__(512) void xg_gemm(
        const float* __restrict__ x, const float* __restrict__ w_ih,
        const float* __restrict__ b_ih, const float* __restrict__ b_hh,
        char* __restrict__ out)
{
    const int tid  = threadIdx.x;
    const int wave = tid >> 6;
    const int lane = tid & 63;
    const int l15  = lane & 15;
    const int kg   = lane >> 4;

    __shared__ short Blds[8192];

    const int m16 = blockIdx.x * 8 + wave;
    const int by  = blockIdx.y;
    const int n0  = by * 256;

    const float* xrow = x + (size_t)(m16 * 16 + l15) * I_N;

    f32x4 acc[16] = {};

#pragma unroll 1
    for (int ks = 0; ks < 8; ++ks) {
        __syncthreads();
#pragma unroll
        for (int h = 0; h < 2; ++h) {
            int nl = (tid >> 2) + h * 128;
            int c  = tid & 3;
            const float* wp = w_ih + (size_t)(n0 + nl) * I_N + ks * 32 + c * 8;
            f32x4 w0 = *(const f32x4*)(wp);
            f32x4 w1 = *(const f32x4*)(wp + 4);
            s16x8 bv;
            bv[0]=f2bf(w0[0]); bv[1]=f2bf(w0[1]); bv[2]=f2bf(w0[2]); bv[3]=f2bf(w0[3]);
            bv[4]=f2bf(w1[0]); bv[5]=f2bf(w1[1]); bv[6]=f2bf(w1[2]); bv[7]=f2bf(w1[3]);
            int dt = nl >> 4;
            int lp = (nl & 15) + 16 * c;
            *(s16x8*)(&Blds[(dt * 64 + lp) * 8]) = bv;
        }
        __syncthreads();
        const float* ap = xrow + ks * 32 + kg * 8;
        f32x4 a0 = *(const f32x4*)(ap);
        f32x4 a1 = *(const f32x4*)(ap + 4);
        s16x8 av;
        av[0]=f2bf(a0[0]); av[1]=f2bf(a0[1]); av[2]=f2bf(a0[2]); av[3]=f2bf(a0[3]);
        av[4]=f2bf(a1[0]); av[5]=f2bf(a1[1]); av[6]=f2bf(a1[2]); av[7]=f2bf(a1[3]);
#pragma unroll
        for (int dt = 0; dt < 16; ++dt) {
            s16x8 bv = *(const s16x8*)(&Blds[(dt * 64 + lane) * 8]);
            acc[dt] = MFMA(av, bv, acc[dt]);
        }
    }

    const int t = m16 >> 2;
    const int g = m16 & 3;
#pragma unroll
    for (int dt = 0; dt < 16; ++dt) {
        int tau = by * 16 + dt;
        int n   = tau * 16 + l15;
        float bias = b_ih[n] + b_hh[n];
        float scale = ((tau >> 4) == 2) ? -C2 : -C1;
        size_t base = (tau < 32)
            ? ((size_t)t * 65536 + (size_t)g * 16384 + (size_t)tau * 512)
            : (HY_BYTES + (size_t)t * 65536 + (size_t)g * 16384 + (size_t)(tau - 32) * 512);
        s16x4 o;
        o[0] = f2bf(scale * (acc[dt][0] + bias));
        o[1] = f2bf(scale * (acc[dt][1] + bias));
        o[2] = f2bf(scale * (acc[dt][2] + bias));
        o[3] = f2bf(scale * (acc[dt][3] + bias));
        *(s16x4*)(out + base + lane * 8) = o;
    }
}

// ---------------------------------------------------------------------------
// Phase 2 v2: r10 structure with DATA-EMBEDDED COUNTERS.  Each lane publishes
// its 4 h values as two u64 words: low 32 = 2 bf16, high 32 = step counter.
// Writer: two relaxed agent stores, NO drain, NO flag.  Reader: polls the
// data words until both counters == exact target (stale/poison never match),
// then uses the data from the same loads.  Eliminates the writer-side
// vmcnt(0), the flag round-trip, and the separate pv load.
// Sticky bounded poll: broken sync -> fast absmax failure, never a hang.
// ---------------------------------------------------------------------------
__global__ __launch_bounds__(512)
__attribute__((amdgpu_waves_per_eu(2, 2)))
void lstm_rec8v2(
        const float* __restrict__ h0, const float* __restrict__ c0,
        const float* __restrict__ w_hh, char* __restrict__ out,
        char* __restrict__ ws)
{
    const int b    = blockIdx.x;       // 0..7
    const int g    = b & 3;
    const int hf   = b >> 2;
    const int tid  = threadIdx.x;
    const int w    = tid >> 6;
    const int lane = tid & 63;
    const int l15  = lane & 15;
    const int kg   = lane >> 4;

    const int tc   = hf * 8 + w;       // my col-tile (0..15)
    const int ptc  = (hf ^ 1) * 8 + w; // partner col-tile staged by this wave
    const int col  = tc * 16 + l15;
    const int pcol = ptc * 16 + l15;

    __shared__ short hlds[2][4096];    // double-buffered 16x256 bf16, swizzled

    u64* exch = (u64*)ws;
    // [parity][wg][wave][lane][2]: parity stride 8192 u64
    const size_t myx = (size_t)b * 1024 + (size_t)w * 128 + (size_t)lane * 2;
    const size_t pbx = (size_t)(b ^ 4) * 1024 + (size_t)w * 128 + (size_t)lane * 2;

    // ---- W fragments: 4 gate tiles, pre-scaled, register-resident ----
    s16x8 wreg[4][8];
#pragma unroll
    for (int q = 0; q < 4; ++q) {
        const int tau = 16 * q + tc;
        const float scale = (q == 2) ? -C2 : -C1;
        const float* wp = w_hh + (size_t)(tau * 16 + l15) * H_N;
#pragma unroll
        for (int ks = 0; ks < 8; ++ks) {
            const float* p = wp + ks * 32 + kg * 8;
            f32x4 w0 = *(const f32x4*)(p);
            f32x4 w1 = *(const f32x4*)(p + 4);
            s16x8 v;
            v[0]=f2bf(scale*w0[0]); v[1]=f2bf(scale*w0[1]);
            v[2]=f2bf(scale*w0[2]); v[3]=f2bf(scale*w0[3]);
            v[4]=f2bf(scale*w1[0]); v[5]=f2bf(scale*w1[1]);
            v[6]=f2bf(scale*w1[2]); v[7]=f2bf(scale*w1[3]);
            wreg[q][ks] = v;
        }
    }

    // ---- h0 -> hlds[0] (full 256 cols, bf16, XOR swizzle per row) ----
    {
        const int row  = tid >> 5;
        const int col0 = (tid & 31) * 8;
        const float* hp = h0 + (size_t)(g * 16 + row) * H_N + col0;
        const int sw = (row & 7) << 4;
#pragma unroll
        for (int j = 0; j < 8; ++j) {
            int byte = row * 512 + ((2 * (col0 + j)) ^ sw);
            *(short*)((char*)hlds[0] + byte) = f2bf(hp[j]);
        }
    }

    // ---- c0 -> registers (my cols only) ----
    float cst[4];
#pragma unroll
    for (int r = 0; r < 4; ++r)
        cst[r] = c0[(size_t)(g * 16 + kg * 4 + r) * H_N + col];

    float hnew[4] = {};
    unsigned dead = 0;    // sticky poll-timeout marker

    __syncthreads();

    const char* p_xg0 = out + (size_t)g * 16384 + (size_t)tc * 512 + (size_t)lane * 8;           // i
    const char* p_xg1 = p_xg0 + 16 * 512;                                                         // f
    const char* p_xg2 = out + HY_BYTES + (size_t)g * 16384 + (size_t)tc * 512 + (size_t)lane * 8; // g
    const char* p_xg3 = p_xg2 + 16 * 512;                                                         // o
    char* st_h = out + (size_t)(g * 16 + kg * 4) * 1024 + (size_t)col * 4;
    char* st_c = st_h + HY_BYTES;

    const int amask = (l15 & 7) << 4;

    s16x4 xg[4];

#define XG_LOAD(T) do {                                                       \
        const size_t _o = ((size_t)(T) << 16);                                \
        xg[0] = ntl4(p_xg0 + _o);  xg[1] = ntl4(p_xg1 + _o);                  \
        xg[2] = ntl4(p_xg2 + _o);  xg[3] = ntl4(p_xg3 + _o);                  \
    } while (0)

    XG_LOAD(0);
    asm volatile("s_waitcnt vmcnt(0)" ::: "memory");

#define STEP(PAR, T) do {                                                     \
        /* h,c outputs of step T-1 (cached stores; never waited on) */        \
        if ((T) > 0) {                                                        \
            char* _hp = st_h + ((size_t)((T) - 1) << 16);                     \
            char* _cp = st_c + ((size_t)((T) - 1) << 16);                     \
            _Pragma("unroll")                                                 \
            for (int r = 0; r < 4; ++r) {                                     \
                *(float*)(_hp + r * 1024) = hnew[r];                          \
                *(float*)(_cp + r * 1024) = cst[r];                           \
            }                                                                 \
        }                                                                     \
        /* acc <- pre-scaled xg fragment (identical layout) */                \
        f32x4 acc[4];                                                         \
        _Pragma("unroll")                                                     \
        for (int q = 0; q < 4; ++q) {                                         \
            acc[q][0] = bf2f(xg[q][0]); acc[q][1] = bf2f(xg[q][1]);           \
            acc[q][2] = bf2f(xg[q][2]); acc[q][3] = bf2f(xg[q][3]);           \
        }                                                                     \
        /* gates += h_T @ (scaled W)^T  (full k=256; W in regs) */            \
        _Pragma("unroll")                                                     \
        for (int ks = 0; ks < 8; ++ks) {                                      \
            s16x8 av = *(const s16x8*)((const char*)hlds[PAR] +               \
                            l15 * 512 + ((ks * 64 + kg * 16) ^ amask));       \
            acc[0] = MFMA(av, wreg[0][ks], acc[0]);                           \
            acc[1] = MFMA(av, wreg[1][ks], acc[1]);                           \
            acc[2] = MFMA(av, wreg[2][ks], acc[2]);                           \
            acc[3] = MFMA(av, wreg[3][ks], acc[3]);                           \
        }                                                                     \
        /* activations (exp2 fed directly by pre-scaled gates) */             \
        unsigned pk0, pk1;                                                    \
        {                                                                     \
            _Pragma("unroll")                                                 \
            for (int r = 0; r < 4; ++r) {                                     \
                float Ei = e2c(acc[0][r]);                                    \
                float Ef = e2c(acc[1][r]);                                    \
                float Eg = e2c(acc[2][r]);                                    \
                float Eo = e2c(acc[3][r]);                                    \
                float ai = 1.0f + Ei, af = 1.0f + Ef;                         \
                float ag = 1.0f + Eg, ao = 1.0f + Eo;                         \
                float r1 = __builtin_amdgcn_rcpf(ai * af);                    \
                float gi = r1 * af;                                           \
                float gf = r1 * ai;                                           \
                float r2 = __builtin_amdgcn_rcpf(ag * ao);                    \
                float go = r2 * ag;                                           \
                float tg = 2.0f * (r2 * ao) - 1.0f;                           \
                float c  = gf * cst[r] + gi * tg;                             \
                cst[r] = c;                                                   \
                float Ec = e2c(-C2 * c);                                      \
                float tc_ = 2.0f * __builtin_amdgcn_rcpf(1.0f + Ec) - 1.0f;   \
                hnew[r] = go * tc_;                                           \
            }                                                                 \
            unsigned s0 = (unsigned short)f2bf(hnew[0]);                      \
            unsigned s1 = (unsigned short)f2bf(hnew[1]);                      \
            unsigned s2 = (unsigned short)f2bf(hnew[2]);                      \
            unsigned s3 = (unsigned short)f2bf(hnew[3]);                      \
            pk0 = s0 | (s1 << 16);                                            \
            pk1 = s2 | (s3 << 16);                                            \
        }                                                                     \
        if ((T) + 1 < T_N) {                                                  \
            /* publish data|ctr fused — fire and forget, NO drain, NO flag */ \
            u64 c64 = ((u64)(unsigned)((T) + 1)) << 32;                       \
            u64* _m = exch + (size_t)(PAR) * 8192 + myx;                      \
            __hip_atomic_store(_m,     (u64)pk0 | c64,                        \
                               __ATOMIC_RELAXED, __HIP_MEMORY_SCOPE_AGENT);   \
            __hip_atomic_store(_m + 1, (u64)pk1 | c64,                        \
                               __ATOMIC_RELAXED, __HIP_MEMORY_SCOPE_AGENT);   \
        }                                                                     \
        /* own-half h -> hlds[PAR^1] */                                       \
        _Pragma("unroll")                                                     \
        for (int r = 0; r < 4; ++r) {                                         \
            int row = kg * 4 + r;                                             \
            int byte = row * 512 + ((2 * col) ^ ((row & 7) << 4));            \
            unsigned v = (r < 2) ? pk0 : pk1;                                 \
            *(short*)((char*)hlds[(PAR) ^ 1] + byte) =                        \
                (short)((r & 1) ? (v >> 16) : v);                             \
        }                                                                     \
        if ((T) + 1 < T_N) {                                                  \
            XG_LOAD((T) + 1);                                                 \
            /* poll partner data directly: both ctrs must equal T+1 */        \
            u64 v0 = 0, v1 = 0;                                               \
            if (!dead) {                                                      \
                const u64* _p = exch + (size_t)(PAR) * 8192 + pbx;            \
                const unsigned tgt = (unsigned)((T) + 1);                     \
                unsigned spins = 0;                                           \
                for (;;) {                                                    \
                    v0 = __hip_atomic_load(_p,     __ATOMIC_RELAXED,          \
                                           __HIP_MEMORY_SCOPE_AGENT);         \
                    v1 = __hip_atomic_load(_p + 1, __ATOMIC_RELAXED,          \
                                           __HIP_MEMORY_SCOPE_AGENT);         \
                    int ok = ((unsigned)(v0 >> 32) == tgt) &                  \
                             ((unsigned)(v1 >> 32) == tgt);                   \
                    if (__all(ok)) break;                                     \
                    __builtin_amdgcn_s_sleep(1);                              \
                    if (++spins > 16384u) { dead = 1; break; }                \
                }                                                             \
            }                                                                 \
            /* stage partner half of h_T into hlds[PAR^1] */                  \
            _Pragma("unroll")                                                 \
            for (int r = 0; r < 4; ++r) {                                     \
                int row = kg * 4 + r;                                         \
                int byte = row * 512 + ((2 * pcol) ^ ((row & 7) << 4));       \
                unsigned v = (r < 2) ? (unsigned)v0 : (unsigned)v1;           \
                *(short*)((char*)hlds[(PAR) ^ 1] + byte) =                    \
                    (short)((r & 1) ? (v >> 16) : v);                         \
            }                                                                 \
        }                                                                     \
        /* single barrier per step: all LDS writes visible */                 \
        asm volatile("s_waitcnt lgkmcnt(0)" ::: "memory");                    \
        __builtin_amdgcn_s_barrier();                                         \
        asm volatile("" ::: "memory");                                        \
    } while (0)

#pragma unroll 1
    for (int tt = 0; tt < T_N; tt += 2) {
        STEP(0, tt);
        STEP(1, tt + 1);
    }

    // epilogue: h,c of last step + final (hy[-1], cy[-1]) for my cols
    {
        char* hp = st_h + ((size_t)(T_N - 1) << 16);
        char* cp = st_c + ((size_t)(T_N - 1) << 16);
        char* fh = out + 2 * HY_BYTES + (size_t)(g * 16 + kg * 4) * 1024 + (size_t)col * 4;
        char* fc = fh + 65536;
#pragma unroll
        for (int r = 0; r < 4; ++r) {
            *(float*)(hp + r * 1024) = hnew[r];
            *(float*)(cp + r * 1024) = cst[r];
            *(float*)(fh + r * 1024) = hnew[r];
            *(float*)(fc + r * 1024) = cst[r];
        }
    }
#undef STEP
#undef XG_LOAD
}

// ---------------------------------------------------------------------------
// Fallback (WS_V1 <= ws < WS_V2): round-10 kernel (proven 5.95 ms).
// ---------------------------------------------------------------------------
__global__ __launch_bounds__(512)
__attribute__((amdgpu_waves_per_eu(2, 2)))
void lstm_rec8(
        const float* __restrict__ h0, const float* __restrict__ c0,
        const float* __restrict__ w_hh, char* __restrict__ out,
        char* __restrict__ ws)
{
    const int b    = blockIdx.x;
    const int g    = b & 3;
    const int hf   = b >> 2;
    const int tid  = threadIdx.x;
    const int w    = tid >> 6;
    const int lane = tid & 63;
    const int l15  = lane & 15;
    const int kg   = lane >> 4;

    const int tc   = hf * 8 + w;
    const int ptc  = (hf ^ 1) * 8 + w;
    const int col  = tc * 16 + l15;
    const int pcol = ptc * 16 + l15;

    __shared__ short hlds[2][4096];

    unsigned long long* exch = (unsigned long long*)ws;
    unsigned* flags = (unsigned*)(ws + EXCH_BYTES);
    const size_t myx = ((size_t)b * 8 + w) * 64 + lane;
    const size_t pbx = ((size_t)(b ^ 4) * 8 + w) * 64 + lane;
    unsigned* myflag = &flags[b * 8 + w];
    unsigned* pflag  = &flags[(b ^ 4) * 8 + w];

    s16x8 wreg[4][8];
#pragma unroll
    for (int q = 0; q < 4; ++q) {
        const int tau = 16 * q + tc;
        const float scale = (q == 2) ? -C2 : -C1;
        const float* wp = w_hh + (size_t)(tau * 16 + l15) * H_N;
#pragma unroll
        for (int ks = 0; ks < 8; ++ks) {
            const float* p = wp + ks * 32 + kg * 8;
            f32x4 w0 = *(const f32x4*)(p);
            f32x4 w1 = *(const f32x4*)(p + 4);
            s16x8 v;
            v[0]=f2bf(scale*w0[0]); v[1]=f2bf(scale*w0[1]);
            v[2]=f2bf(scale*w0[2]); v[3]=f2bf(scale*w0[3]);
            v[4]=f2bf(scale*w1[0]); v[5]=f2bf(scale*w1[1]);
            v[6]=f2bf(scale*w1[2]); v[7]=f2bf(scale*w1[3]);
            wreg[q][ks] = v;
        }
    }

    {
        const int row  = tid >> 5;
        const int col0 = (tid & 31) * 8;
        const float* hp = h0 + (size_t)(g * 16 + row) * H_N + col0;
        const int sw = (row & 7) << 4;
#pragma unroll
        for (int j = 0; j < 8; ++j) {
            int byte = row * 512 + ((2 * (col0 + j)) ^ sw);
            *(short*)((char*)hlds[0] + byte) = f2bf(hp[j]);
        }
    }

    float cst[4];
#pragma unroll
    for (int r = 0; r < 4; ++r)
        cst[r] = c0[(size_t)(g * 16 + kg * 4 + r) * H_N + col];

    float hnew[4] = {};
    unsigned dead = 0;

    __syncthreads();

    const char* p_xg0 = out + (size_t)g * 16384 + (size_t)tc * 512 + (size_t)lane * 8;
    const char* p_xg1 = p_xg0 + 16 * 512;
    const char* p_xg2 = out + HY_BYTES + (size_t)g * 16384 + (size_t)tc * 512 + (size_t)lane * 8;
    const char* p_xg3 = p_xg2 + 16 * 512;
    char* st_h = out + (size_t)(g * 16 + kg * 4) * 1024 + (size_t)col * 4;
    char* st_c = st_h + HY_BYTES;

    const int amask = (l15 & 7) << 4;

    s16x4 xg[4];

#define XG_LOAD(T) do {                                                       \
        const size_t _o = ((size_t)(T) << 16);                                \
        xg[0] = ntl4(p_xg0 + _o);  xg[1] = ntl4(p_xg1 + _o);                  \
        xg[2] = ntl4(p_xg2 + _o);  xg[3] = ntl4(p_xg3 + _o);                  \
    } while (0)

    XG_LOAD(0);
    asm volatile("s_waitcnt vmcnt(0)" ::: "memory");

#define STEP(PAR, T) do {                                                     \
        if ((T) > 0) {                                                        \
            char* _hp = st_h + ((size_t)((T) - 1) << 16);                     \
            char* _cp = st_c + ((size_t)((T) - 1) << 16);                     \
            _Pragma("unroll")                                                 \
            for (int r = 0; r < 4; ++r) {                                     \
                *(float*)(_hp + r * 1024) = hnew[r];                          \
                *(float*)(_cp + r * 1024) = cst[r];                           \
            }                                                                 \
        }                                                                     \
        unsigned fv = __hip_atomic_load(pflag, __ATOMIC_RELAXED,              \
                                        __HIP_MEMORY_SCOPE_AGENT);            \
        f32x4 acc[4];                                                         \
        _Pragma("unroll")                                                     \
        for (int q = 0; q < 4; ++q) {                                         \
            acc[q][0] = bf2f(xg[q][0]); acc[q][1] = bf2f(xg[q][1]);           \
            acc[q][2] = bf2f(xg[q][2]); acc[q][3] = bf2f(xg[q][3]);           \
        }                                                                     \
        _Pragma("unroll")                                                     \
        for (int ks = 0; ks < 8; ++ks) {                                      \
            s16x8 av = *(const s16x8*)((const char*)hlds[PAR] +               \
                            l15 * 512 + ((ks * 64 + kg * 16) ^ amask));       \
            acc[0] = MFMA(av, wreg[0][ks], acc[0]);                           \
            acc[1] = MFMA(av, wreg[1][ks], acc[1]);                           \
            acc[2] = MFMA(av, wreg[2][ks], acc[2]);                           \
            acc[3] = MFMA(av, wreg[3][ks], acc[3]);                           \
        }                                                                     \
        unsigned pk0, pk1;                                                    \
        {                                                                     \
            _Pragma("unroll")                                                 \
            for (int r = 0; r < 4; ++r) {                                     \
                float Ei = e2c(acc[0][r]);                                    \
                float Ef = e2c(acc[1][r]);                                    \
                float Eg = e2c(acc[2][r]);                                    \
                float Eo = e2c(acc[3][r]);                                    \
                float ai = 1.0f + Ei, af = 1.0f + Ef;                         \
                float ag = 1.0f + Eg, ao = 1.0f + Eo;                         \
                float r1 = __builtin_amdgcn_rcpf(ai * af);                    \
                float gi = r1 * af;                                           \
                float gf = r1 * ai;                                           \
                float r2 = __builtin_amdgcn_rcpf(ag * ao);                    \
                float go = r2 * ag;                                           \
                float tg = 2.0f * (r2 * ao) - 1.0f;                           \
                float c  = gf * cst[r] + gi * tg;                             \
                cst[r] = c;                                                   \
                float Ec = e2c(-C2 * c);                                      \
                float tc_ = 2.0f * __builtin_amdgcn_rcpf(1.0f + Ec) - 1.0f;   \
                hnew[r] = go * tc_;                                           \
            }                                                                 \
            unsigned s0 = (unsigned short)f2bf(hnew[0]);                      \
            unsigned s1 = (unsigned short)f2bf(hnew[1]);                      \
            unsigned s2 = (unsigned short)f2bf(hnew[2]);                      \
            unsigned s3 = (unsigned short)f2bf(hnew[3]);                      \
            pk0 = s0 | (s1 << 16);                                            \
            pk1 = s2 | (s3 << 16);                                            \
            _Pragma("unroll")                                                 \
            for (int r = 0; r < 4; ++r) {                                     \
                int row = kg * 4 + r;                                         \
                int byte = row * 512 + ((2 * col) ^ ((row & 7) << 4));        \
                unsigned v = (r < 2) ? pk0 : pk1;                             \
                *(short*)((char*)hlds[(PAR) ^ 1] + byte) =                    \
                    (short)((r & 1) ? (v >> 16) : v);                         \
            }                                                                 \
        }                                                                     \
        if ((T) + 1 < T_N) {                                                  \
            unsigned long long val = ((unsigned long long)pk1 << 32) | pk0;   \
            __hip_atomic_store(exch + (size_t)(PAR) * 4096 + myx, val,        \
                               __ATOMIC_RELAXED, __HIP_MEMORY_SCOPE_AGENT);   \
            asm volatile("s_waitcnt vmcnt(0)" ::: "memory");                  \
            if (lane == 0)                                                    \
                __hip_atomic_store(myflag, (unsigned)((T) + 1),               \
                                   __ATOMIC_RELAXED,                          \
                                   __HIP_MEMORY_SCOPE_AGENT);                 \
            XG_LOAD((T) + 1);                                                 \
            if (fv < (unsigned)((T) + 1) && !dead) {                          \
                unsigned spins = 0;                                           \
                while (__hip_atomic_load(pflag, __ATOMIC_RELAXED,             \
                                         __HIP_MEMORY_SCOPE_AGENT)           \
                       < (unsigned)((T) + 1)) {                               \
                    __builtin_amdgcn_s_sleep(1);                              \
                    if (++spins > 16384u) { dead = 1; break; }                \
                }                                                             \
            }                                                                 \
            unsigned long long pv = __hip_atomic_load(                        \
                exch + (size_t)(PAR) * 4096 + pbx,                            \
                __ATOMIC_RELAXED, __HIP_MEMORY_SCOPE_AGENT);                  \
            _Pragma("unroll")                                                 \
            for (int r = 0; r < 4; ++r) {                                     \
                int row = kg * 4 + r;                                         \
                int byte = row * 512 + ((2 * pcol) ^ ((row & 7) << 4));       \
                *(short*)((char*)hlds[(PAR) ^ 1] + byte) =                    \
                    (short)(pv >> (16 * r));                                  \
            }                                                                 \
        }                                                                     \
        asm volatile("s_waitcnt lgkmcnt(0)" ::: "memory");                    \
        __builtin_amdgcn_s_barrier();                                         \
        asm volatile("" ::: "memory");                                        \
    } while (0)

#pragma unroll 1
    for (int tt = 0; tt < T_N; tt += 2) {
        STEP(0, tt);
        STEP(1, tt + 1);
    }

    {
        char* hp = st_h + ((size_t)(T_N - 1) << 16);
        char* cp = st_c + ((size_t)(T_N - 1) << 16);
        char* fh = out + 2 * HY_BYTES + (size_t)(g * 16 + kg * 4) * 1024 + (size_t)col * 4;
        char* fc = fh + 65536;
#pragma unroll
        for (int r = 0; r < 4; ++r) {
            *(float*)(hp + r * 1024) = hnew[r];
            *(float*)(cp + r * 1024) = cst[r];
            *(float*)(fh + r * 1024) = hnew[r];
            *(float*)(fc + r * 1024) = cst[r];
        }
    }
#undef STEP
#undef XG_LOAD
}

extern "C" void kernel_launch(void* const* d_in, const int* in_sizes, int n_in,
                              void* d_out, int out_size, void* d_ws, size_t ws_size,
                              hipStream_t stream) {
    (void)in_sizes; (void)n_in; (void)out_size;
    const float* x    = (const float*)d_in[0];
    const float* h0   = (const float*)d_in[1];
    const float* c0   = (const float*)d_in[2];
    const float* w_ih = (const float*)d_in[3];
    const float* w_hh = (const float*)d_in[4];
    const float* b_ih = (const float*)d_in[5];
    const float* b_hh = (const float*)d_in[6];
    char* out = (char*)d_out;

    if (ws_size >= WS_V2) {
        // data-embedded counters: exact-match compare makes any stale/poison
        // content harmless -> no flag-zeroing launch needed
        xg_gemm<<<dim3(1024, 4), 512, 0, stream>>>(x, w_ih, b_ih, b_hh, out);
        lstm_rec8v2<<<8, 512, 0, stream>>>(h0, c0, w_hh, out, (char*)d_ws);
    } else {
        zero_flags<<<1, 64, 0, stream>>>((char*)d_ws);
        xg_gemm<<<dim3(1024, 4), 512, 0, stream>>>(x, w_ih, b_ih, b_hh, out);
        lstm_rec8<<<8, 512, 0, stream>>>(h0, c0, w_hh, out, (char*)d_ws);
    }
}